// Round 4
// baseline (1047.301 us; speedup 1.0000x reference)
//
#include <hip/hip_runtime.h>
#include <hip/hip_bf16.h>

// HeteroSAGE collapsed pipeline (float32 I/O, bf16 MFMA + bf16 intermediates):
//   out[i] = mean_cites(s_c[src]) + mean_writes(s_w[src]) + s_r[i] + C0
//   s_c = p1.(W2l_c@Wh), s_r = p1.((W2r_c+W2r_w)@Wh), s_w = a1.(W2l_w@Wh)
//   p1 = relu(mean_c(YpC[src]) + mean_w(YaW[src]) + YpD + b1c + b1w)
//   a1 = relu(mean_r(YpR[src]) + YaD + b1rev)
// Edge handling: deterministic per-block bucket partition (LDS-staged, bulk
// coalesced writes, NO global atomics) + per-bucket LDS aggregation with
// stride-33 padding (round-3 had a structural 16-way bank conflict at stride 32).

#define NPART 127
#define SPAN  7936        // 31*256; NPART*SPAN >= 1M
#define NBK   782         // paper: 256-node buckets (>>8); author: 128-node (>>7)
#define SMASK 0x3FFFF     // 18-bit src index (max 200000 < 2^18)

typedef __bf16 bf16x8 __attribute__((ext_vector_type(8)));
typedef float f32x4 __attribute__((ext_vector_type(4)));

// ---------------- prep: combined transposed weights (f32 -> bf16) + head vecs --
__global__ void prep_kernel(const float* W1l_c, const float* W1l_rev,
                            const float* W1r_c, const float* W1r_w,
                            const float* W1l_w, const float* W1r_rev,
                            const float* W2l_c, const float* W2l_w,
                            const float* W2r_c, const float* W2r_w,
                            const float* b2l_c, const float* b2l_w,
                            const float* Wh, const float* bh,
                            __bf16* Bp_t, __bf16* Ba_t, float* uvec) {
    int t = threadIdx.x;
    for (int idx = t; idx < 96 * 128; idx += 256) {   // Bp_t[n][k] n<96,k<128
        int n = idx >> 7, k = idx & 127;
        float v;
        if (n < 32)      v = W1l_c[k * 32 + n];
        else if (n < 64) v = W1l_rev[k * 32 + (n - 32)];
        else             v = W1r_c[k * 32 + (n - 64)] + W1r_w[k * 32 + (n - 64)];
        Bp_t[n * 128 + k] = (__bf16)v;
    }
    for (int idx = t; idx < 64 * 64; idx += 256) {    // Ba_t[n][k] n<64,k<64
        int n = idx >> 6, k = idx & 63;
        float v = (n < 32) ? W1l_w[k * 32 + n] : W1r_rev[k * 32 + (n - 32)];
        Ba_t[n * 64 + k] = (__bf16)v;
    }
    if (t < 32) {
        float uc = 0.f, uw = 0.f, ur = 0.f;
        for (int j = 0; j < 32; ++j) {
            float wh = Wh[j];
            uc += W2l_c[t * 32 + j] * wh;
            uw += W2l_w[t * 32 + j] * wh;
            ur += (W2r_c[t * 32 + j] + W2r_w[t * 32 + j]) * wh;
        }
        uvec[t] = uc; uvec[32 + t] = uw; uvec[64 + t] = ur;
        if (t == 0) {
            float c0 = bh[0];
            for (int j = 0; j < 32; ++j) c0 += (b2l_c[j] + b2l_w[j]) * Wh[j];
            uvec[96] = c0;
        }
    }
}

// ---------------- projection GEMM: split 32-col groups to separate arrays ------
template <int K, int NG>
__global__ __launch_bounds__(256) void proj_kernel(const float* __restrict__ X,
                                                   const __bf16* __restrict__ Bt,
                                                   __bf16* __restrict__ D0,
                                                   __bf16* __restrict__ D1,
                                                   __bf16* __restrict__ D2, int M) {
    constexpr int NT = NG * 2, KT = K / 32;
    int lane = threadIdx.x & 63;
    int wave = (blockIdx.x * 256 + threadIdx.x) >> 6;
    int m0 = wave * 16;
    if (m0 + 16 > M) return;  // M % 16 == 0 here
    int lr = lane & 15;
    int quad = lane >> 4;

    bf16x8 bfrag[NT][KT];
#pragma unroll
    for (int ct = 0; ct < NT; ++ct)
#pragma unroll
        for (int ks = 0; ks < KT; ++ks)
            bfrag[ct][ks] = *(const bf16x8*)(Bt + (ct * 16 + lr) * K + ks * 32 + quad * 8);

    bf16x8 afrag[KT];
    const float* xrow = X + (size_t)(m0 + lr) * K + quad * 8;
#pragma unroll
    for (int ks = 0; ks < KT; ++ks) {
        f32x4 lo = *(const f32x4*)(xrow + ks * 32);
        f32x4 hi = *(const f32x4*)(xrow + ks * 32 + 4);
        bf16x8 a;
#pragma unroll
        for (int j = 0; j < 4; ++j) { a[j] = (__bf16)lo[j]; a[4 + j] = (__bf16)hi[j]; }
        afrag[ks] = a;
    }

#pragma unroll
    for (int ct = 0; ct < NT; ++ct) {
        f32x4 acc = {0.f, 0.f, 0.f, 0.f};
#pragma unroll
        for (int ks = 0; ks < KT; ++ks)
            acc = __builtin_amdgcn_mfma_f32_16x16x32_bf16(afrag[ks], bfrag[ct][ks], acc, 0, 0, 0);
        __bf16* D = ((ct >> 1) == 0) ? D0 : (((ct >> 1) == 1) ? D1 : D2);
        int col = (ct & 1) * 16 + lr;
        int rbase = m0 + quad * 4;
#pragma unroll
        for (int r = 0; r < 4; ++r)
            D[(size_t)(rbase + r) * 32 + col] = (__bf16)acc[r];
    }
}

// ---------------- deterministic partition: per-block bucket sort ---------------
// Block handles edges [blk*SPAN, min(E,(blk+1)*SPAN)) of relation `rel`.
// Output: ebuf[rel_blk_base + local_offset], fully coalesced bulk copy.
// dir[(rel*NPART+blk)*NBK + b] = (absolute start, count).
__global__ __launch_bounds__(256) void part_kernel(
    const int* __restrict__ eiC, const int* __restrict__ eiW, const int* __restrict__ eiR,
    unsigned* __restrict__ ebuf, int2* __restrict__ dir, int E) {
    __shared__ unsigned stage[SPAN];
    __shared__ int cnt[1024];
    __shared__ int tsum[256];
    int rel = blockIdx.x / NPART, blk = blockIdx.x % NPART;
    const int* ei = rel == 0 ? eiC : (rel == 1 ? eiW : eiR);
    int shift = (rel == 2) ? 7 : 8;
    int t = threadIdx.x;
    int e0 = blk * SPAN, e1 = min(E, e0 + SPAN);
    for (int i = t; i < 1024; i += 256) cnt[i] = 0;
    __syncthreads();
    for (int e = e0 + t; e < e1; e += 256) atomicAdd(&cnt[ei[E + e] >> shift], 1);
    __syncthreads();
    int c0 = cnt[t * 4], c1 = cnt[t * 4 + 1], c2 = cnt[t * 4 + 2], c3 = cnt[t * 4 + 3];
    int s = c0 + c1 + c2 + c3;
    tsum[t] = s;
    __syncthreads();
    for (int d = 1; d < 256; d <<= 1) {
        int v = tsum[t] + ((t >= d) ? tsum[t - d] : 0);
        __syncthreads(); tsum[t] = v; __syncthreads();
    }
    int excl = tsum[t] - s;
    cnt[t * 4] = excl; cnt[t * 4 + 1] = excl + c0;
    cnt[t * 4 + 2] = excl + c0 + c1; cnt[t * 4 + 3] = excl + c0 + c1 + c2;
    int base = (rel * NPART + blk) * SPAN;
    int dbase = (rel * NPART + blk) * NBK;
    int off[4] = {excl, excl + c0, excl + c0 + c1, excl + c0 + c1 + c2};
    int cc[4] = {c0, c1, c2, c3};
#pragma unroll
    for (int j = 0; j < 4; ++j) {
        int b = t * 4 + j;
        if (b < NBK) dir[dbase + b] = make_int2(base + off[j], cc[j]);
    }
    __syncthreads();
    unsigned msk = (1u << shift) - 1;
    for (int e = e0 + t; e < e1; e += 256) {
        int d_ = ei[E + e], s_ = ei[e];
        int pos = atomicAdd(&cnt[d_ >> shift], 1);
        stage[pos] = ((unsigned)(d_ & msk) << 18) | (unsigned)s_;
    }
    __syncthreads();
    for (int i = t; i < e1 - e0; i += 256) ebuf[base + i] = stage[i];
}

// ---------------- paper aggregation: cites + writes means -> p1 -> s_c,s_r -----
__global__ __launch_bounds__(256) void agg_paper_kernel(
    const __bf16* __restrict__ YpC, const __bf16* __restrict__ YaW,
    const __bf16* __restrict__ YpD,
    const unsigned* __restrict__ ebuf, const int2* __restrict__ dir,
    const float* __restrict__ b1l_c, const float* __restrict__ b1l_w,
    const float* __restrict__ uvec,
    float* __restrict__ s_c, float* __restrict__ s_r, int NP) {
    __shared__ float acc[256 * 33];   // stride 33: bank = (dl + sc + j) & 31, ~2-way
    __shared__ int cntN[256];
    int b = blockIdx.x, t = threadIdx.x;
    int lane = t & 63, wv = t >> 6;
    int eq = lane >> 2, sc = (lane & 3) * 8;   // 16 edges/wave-iter, 4 lanes/edge
    for (int i = t; i < 256 * 33; i += 256) acc[i] = 0.f;
    cntN[t & 255] = 0;
    __syncthreads();
    float mC[32];
    int c = t & 31, nl = t >> 5;
    for (int rel = 0; rel < 2; ++rel) {
        const __bf16* S = rel ? YaW : YpC;
        for (int blkk = wv; blkk < NPART; blkk += 4) {
            int2 d2 = dir[(rel * NPART + blkk) * NBK + b];
            for (int i0 = 0; i0 < d2.y; i0 += 16) {
                int e = i0 + eq;
                if (e < d2.y) {
                    unsigned w = ebuf[d2.x + e];
                    int dl = w >> 18, si = w & SMASK;
                    bf16x8 v = *(const bf16x8*)(S + (size_t)si * 32 + sc);
                    float* ap = acc + dl * 33 + sc;
#pragma unroll
                    for (int j = 0; j < 8; ++j) unsafeAtomicAdd(ap + j, (float)v[j]);
                    if (sc == 0) atomicAdd(&cntN[dl], 1);
                }
            }
        }
        __syncthreads();
        if (rel == 0) {
#pragma unroll
            for (int k = 0; k < 32; ++k) {
                int n = k * 8 + nl;
                mC[k] = acc[n * 33 + c] / (float)max(cntN[n], 1);
            }
            __syncthreads();
            for (int i = t; i < 256 * 33; i += 256) acc[i] = 0.f;
            cntN[t & 255] = 0;
            __syncthreads();
        }
    }
    float bc = b1l_c[c] + b1l_w[c];
    float uc = uvec[c], ur = uvec[64 + c];
#pragma unroll
    for (int k = 0; k < 32; ++k) {
        int n = k * 8 + nl;
        int gn = b * 256 + n;
        if (gn < NP) {
            float mW = acc[n * 33 + c] / (float)max(cntN[n], 1);
            float p = mC[k] + mW + (float)YpD[(size_t)gn * 32 + c] + bc;
            p = fmaxf(p, 0.f);
            float vc = p * uc, vr = p * ur;
            for (int m = 1; m < 32; m <<= 1) {
                vc += __shfl_xor(vc, m, 64); vr += __shfl_xor(vr, m, 64);
            }
            if (c == 0) { s_c[gn] = vc; s_r[gn] = vr; }
        }
    }
}

// ---------------- author aggregation: rev mean -> a1 -> s_w --------------------
__global__ __launch_bounds__(256) void agg_author_kernel(
    const __bf16* __restrict__ YpR, const __bf16* __restrict__ YaD,
    const unsigned* __restrict__ ebuf, const int2* __restrict__ dir,
    const float* __restrict__ b1l_r, const float* __restrict__ uvec,
    float* __restrict__ s_w, int NA) {
    __shared__ float acc[128 * 33];
    __shared__ int cntN[128];
    int b = blockIdx.x, t = threadIdx.x;
    int lane = t & 63, wv = t >> 6;
    int eq = lane >> 2, sc = (lane & 3) * 8;
    for (int i = t; i < 128 * 33; i += 256) acc[i] = 0.f;
    if (t < 128) cntN[t] = 0;
    __syncthreads();
    for (int blkk = wv; blkk < NPART; blkk += 4) {
        int2 d2 = dir[(2 * NPART + blkk) * NBK + b];
        for (int i0 = 0; i0 < d2.y; i0 += 16) {
            int e = i0 + eq;
            if (e < d2.y) {
                unsigned w = ebuf[d2.x + e];
                int dl = w >> 18, si = w & SMASK;
                bf16x8 v = *(const bf16x8*)(YpR + (size_t)si * 32 + sc);
                float* ap = acc + dl * 33 + sc;
#pragma unroll
                for (int j = 0; j < 8; ++j) unsafeAtomicAdd(ap + j, (float)v[j]);
                if (sc == 0) atomicAdd(&cntN[dl], 1);
            }
        }
    }
    __syncthreads();
    int c = t & 31, nl = t >> 5;
    float br = b1l_r[c], uw = uvec[32 + c];
#pragma unroll
    for (int k = 0; k < 16; ++k) {
        int n = k * 8 + nl;
        int ga = b * 128 + n;
        if (ga < NA) {
            float mR = acc[n * 33 + c] / (float)max(cntN[n], 1);
            float p = mR + (float)YaD[(size_t)ga * 32 + c] + br;
            p = fmaxf(p, 0.f);
            float vw = p * uw;
            for (int m = 1; m < 32; m <<= 1) vw += __shfl_xor(vw, m, 64);
            if (c == 0) s_w[ga] = vw;
        }
    }
}

// ---------------- layer-2 scalar aggregation + output --------------------------
__global__ __launch_bounds__(256) void out_kernel(
    const float* __restrict__ s_c, const float* __restrict__ s_w,
    const float* __restrict__ s_r,
    const unsigned* __restrict__ ebuf, const int2* __restrict__ dir,
    const float* __restrict__ uvec, float* __restrict__ out, int NP) {
    __shared__ float a2[2][256];
    __shared__ int c2[2][256];
    int b = blockIdx.x, t = threadIdx.x;
    int lane = t & 63, wv = t >> 6;
    a2[0][t] = 0.f; a2[1][t] = 0.f; c2[0][t] = 0; c2[1][t] = 0;
    __syncthreads();
    for (int rel = 0; rel < 2; ++rel) {
        const float* S = rel ? s_w : s_c;
        for (int blkk = wv; blkk < NPART; blkk += 4) {
            int2 d2 = dir[(rel * NPART + blkk) * NBK + b];
            for (int i0 = 0; i0 < d2.y; i0 += 64) {
                int e = i0 + lane;
                if (e < d2.y) {
                    unsigned w = ebuf[d2.x + e];
                    unsafeAtomicAdd(&a2[rel][w >> 18], S[w & SMASK]);
                    atomicAdd(&c2[rel][w >> 18], 1);
                }
            }
        }
    }
    __syncthreads();
    int gn = b * 256 + t;
    if (gn < NP)
        out[gn] = a2[0][t] / (float)max(c2[0][t], 1)
                + a2[1][t] / (float)max(c2[1][t], 1) + s_r[gn] + uvec[96];
}

extern "C" void kernel_launch(void* const* d_in, const int* in_sizes, int n_in,
                              void* d_out, int out_size, void* d_ws, size_t ws_size,
                              hipStream_t stream) {
    const float* x_paper  = (const float*)d_in[0];
    const float* x_author = (const float*)d_in[1];
    const int* eiC = (const int*)d_in[2];
    const int* eiW = (const int*)d_in[3];
    const int* eiR = (const int*)d_in[4];
    const float* W1l_c  = (const float*)d_in[5];
    const float* b1l_c  = (const float*)d_in[6];
    const float* W1r_c  = (const float*)d_in[7];
    const float* W1l_w  = (const float*)d_in[8];
    const float* b1l_w  = (const float*)d_in[9];
    const float* W1r_w  = (const float*)d_in[10];
    const float* W1l_r  = (const float*)d_in[11];
    const float* b1l_r  = (const float*)d_in[12];
    const float* W1r_r  = (const float*)d_in[13];
    const float* W2l_c  = (const float*)d_in[14];
    const float* b2l_c  = (const float*)d_in[15];
    const float* W2r_c  = (const float*)d_in[16];
    const float* W2l_w  = (const float*)d_in[17];
    const float* b2l_w  = (const float*)d_in[18];
    const float* W2r_w  = (const float*)d_in[19];
    // d_in[20..22] unused (author layer-2 output not consumed)
    const float* Wh = (const float*)d_in[23];
    const float* bh = (const float*)d_in[24];

    const int NP = in_sizes[0] / 128;
    const int NA = in_sizes[1] / 64;
    const int E  = in_sizes[2] / 2;
    const int NBKp = (NP + 255) >> 8;   // 782
    const int NBKa = (NA + 127) >> 7;   // 782

    char* p = (char*)d_ws;
    auto alloc = [&](size_t bytes) -> void* {
        void* r = (void*)p;
        p += (bytes + 255) & ~(size_t)255;
        return r;
    };
    __bf16* YpC = (__bf16*)alloc((size_t)NP * 32 * 2);
    __bf16* YpR = (__bf16*)alloc((size_t)NP * 32 * 2);
    __bf16* YpD = (__bf16*)alloc((size_t)NP * 32 * 2);
    __bf16* YaW = (__bf16*)alloc((size_t)NA * 32 * 2);
    __bf16* YaD = (__bf16*)alloc((size_t)NA * 32 * 2);
    __bf16* Bp_t = (__bf16*)alloc(96 * 128 * 2);
    __bf16* Ba_t = (__bf16*)alloc(64 * 64 * 2);
    float* uvec = (float*)alloc(128 * 4);
    float* s_c  = (float*)alloc((size_t)NP * 4);
    float* s_r  = (float*)alloc((size_t)NP * 4);
    float* s_w  = (float*)alloc((size_t)NA * 4);
    unsigned* ebuf = (unsigned*)alloc((size_t)3 * NPART * SPAN * 4);   // 12.1 MB
    int2* dir      = (int2*)alloc((size_t)3 * NPART * NBK * 8);        // 2.4 MB

    prep_kernel<<<1, 256, 0, stream>>>(W1l_c, W1l_r, W1r_c, W1r_w, W1l_w, W1r_r,
                                       W2l_c, W2l_w, W2r_c, W2r_w, b2l_c, b2l_w,
                                       Wh, bh, Bp_t, Ba_t, uvec);

    proj_kernel<128, 3><<<(NP + 63) / 64, 256, 0, stream>>>(x_paper, Bp_t, YpC, YpR, YpD, NP);
    proj_kernel<64, 2><<<(NA + 63) / 64, 256, 0, stream>>>(x_author, Ba_t, YaW, YaD, nullptr, NA);

    part_kernel<<<3 * NPART, 256, 0, stream>>>(eiC, eiW, eiR, ebuf, dir, E);

    agg_paper_kernel<<<NBKp, 256, 0, stream>>>(YpC, YaW, YpD, ebuf, dir,
                                               b1l_c, b1l_w, uvec, s_c, s_r, NP);
    agg_author_kernel<<<NBKa, 256, 0, stream>>>(YpR, YaD, ebuf, dir, b1l_r, uvec, s_w, NA);
    out_kernel<<<NBKp, 256, 0, stream>>>(s_c, s_w, s_r, ebuf, dir, uvec, (float*)d_out, NP);
}

// Round 5
// 958.779 us; speedup vs baseline: 1.0923x; 1.0923x over previous
//
#include <hip/hip_runtime.h>
#include <hip/hip_bf16.h>

// HeteroSAGE collapsed pipeline (float32 I/O, bf16 MFMA + bf16 intermediates):
//   out[i] = mean_cites(s_c[src]) + mean_writes(s_w[src]) + s_r[i] + C0
//   s_c = p1.(W2l_c@Wh), s_r = p1.((W2r_c+W2r_w)@Wh), s_w = a1.(W2l_w@Wh)
//   p1 = relu(mean_c(YpC[src]) + mean_w(YaW[src]) + YpD + b1c + b1w)
//   a1 = relu(mean_r(YpR[src]) + YaD + b1rev)
// Edge handling (round-5): exact bucket-granular regroup. 1563 buckets per
// relation (paper: 128 nodes, author: 64). hist -> scan -> scatter produces
// ebuf with each bucket's edges CONTIGUOUS (round-4's 127 scattered 10-edge
// segments per bucket caused pure latency serialization: 276 GB/s, VALU 5%).
// Aggregation: one block per bucket, lane-per-edge, 2x unrolled gathers,
// stride-33 LDS accumulators (round-3's stride-32 was 16-way conflicted).

#define SPAN  8192
#define NBKT  1563        // ceil(200000/128) == ceil(100000/64)
#define SMASK 0x3FFFF     // 18-bit src index (200000 < 2^18)

typedef __bf16 bf16x8 __attribute__((ext_vector_type(8)));
typedef float f32x4 __attribute__((ext_vector_type(4)));

// ---------------- prep: combined transposed weights (f32 -> bf16) + head vecs --
__global__ void prep_kernel(const float* W1l_c, const float* W1l_rev,
                            const float* W1r_c, const float* W1r_w,
                            const float* W1l_w, const float* W1r_rev,
                            const float* W2l_c, const float* W2l_w,
                            const float* W2r_c, const float* W2r_w,
                            const float* b2l_c, const float* b2l_w,
                            const float* Wh, const float* bh,
                            __bf16* Bp_t, __bf16* Ba_t, float* uvec) {
    int t = threadIdx.x;
    for (int idx = t; idx < 96 * 128; idx += 256) {   // Bp_t[n][k] n<96,k<128
        int n = idx >> 7, k = idx & 127;
        float v;
        if (n < 32)      v = W1l_c[k * 32 + n];
        else if (n < 64) v = W1l_rev[k * 32 + (n - 32)];
        else             v = W1r_c[k * 32 + (n - 64)] + W1r_w[k * 32 + (n - 64)];
        Bp_t[n * 128 + k] = (__bf16)v;
    }
    for (int idx = t; idx < 64 * 64; idx += 256) {    // Ba_t[n][k] n<64,k<64
        int n = idx >> 6, k = idx & 63;
        float v = (n < 32) ? W1l_w[k * 32 + n] : W1r_rev[k * 32 + (n - 32)];
        Ba_t[n * 64 + k] = (__bf16)v;
    }
    if (t < 32) {
        float uc = 0.f, uw = 0.f, ur = 0.f;
        for (int j = 0; j < 32; ++j) {
            float wh = Wh[j];
            uc += W2l_c[t * 32 + j] * wh;
            uw += W2l_w[t * 32 + j] * wh;
            ur += (W2r_c[t * 32 + j] + W2r_w[t * 32 + j]) * wh;
        }
        uvec[t] = uc; uvec[32 + t] = uw; uvec[64 + t] = ur;
        if (t == 0) {
            float c0 = bh[0];
            for (int j = 0; j < 32; ++j) c0 += (b2l_c[j] + b2l_w[j]) * Wh[j];
            uvec[96] = c0;
        }
    }
}

// ---------------- projection GEMM: split 32-col groups to separate arrays ------
template <int K, int NG>
__global__ __launch_bounds__(256) void proj_kernel(const float* __restrict__ X,
                                                   const __bf16* __restrict__ Bt,
                                                   __bf16* __restrict__ D0,
                                                   __bf16* __restrict__ D1,
                                                   __bf16* __restrict__ D2, int M) {
    constexpr int NT = NG * 2, KT = K / 32;
    int lane = threadIdx.x & 63;
    int wave = (blockIdx.x * 256 + threadIdx.x) >> 6;
    int m0 = wave * 16;
    if (m0 + 16 > M) return;  // M % 16 == 0 here
    int lr = lane & 15;
    int quad = lane >> 4;

    bf16x8 bfrag[NT][KT];
#pragma unroll
    for (int ct = 0; ct < NT; ++ct)
#pragma unroll
        for (int ks = 0; ks < KT; ++ks)
            bfrag[ct][ks] = *(const bf16x8*)(Bt + (ct * 16 + lr) * K + ks * 32 + quad * 8);

    bf16x8 afrag[KT];
    const float* xrow = X + (size_t)(m0 + lr) * K + quad * 8;
#pragma unroll
    for (int ks = 0; ks < KT; ++ks) {
        f32x4 lo = *(const f32x4*)(xrow + ks * 32);
        f32x4 hi = *(const f32x4*)(xrow + ks * 32 + 4);
        bf16x8 a;
#pragma unroll
        for (int j = 0; j < 4; ++j) { a[j] = (__bf16)lo[j]; a[4 + j] = (__bf16)hi[j]; }
        afrag[ks] = a;
    }

#pragma unroll
    for (int ct = 0; ct < NT; ++ct) {
        f32x4 acc = {0.f, 0.f, 0.f, 0.f};
#pragma unroll
        for (int ks = 0; ks < KT; ++ks)
            acc = __builtin_amdgcn_mfma_f32_16x16x32_bf16(afrag[ks], bfrag[ct][ks], acc, 0, 0, 0);
        __bf16* D = ((ct >> 1) == 0) ? D0 : (((ct >> 1) == 1) ? D1 : D2);
        int col = (ct & 1) * 16 + lr;
        int rbase = m0 + quad * 4;
#pragma unroll
        for (int r = 0; r < 4; ++r)
            D[(size_t)(rbase + r) * 32 + col] = (__bf16)acc[r];
    }
}

// ---------------- pass 1: per-span LDS histogram -> global bucket counts -------
__global__ __launch_bounds__(256) void hist_kernel(
    const int* __restrict__ eiC, const int* __restrict__ eiW, const int* __restrict__ eiR,
    int* __restrict__ bcnt, int E, int npart) {
    __shared__ int cnt[NBKT];
    int rel = blockIdx.x / npart, blk = blockIdx.x % npart;
    const int* ei = rel == 0 ? eiC : (rel == 1 ? eiW : eiR);
    int shift = (rel == 2) ? 6 : 7;
    int t = threadIdx.x;
    for (int i = t; i < NBKT; i += 256) cnt[i] = 0;
    __syncthreads();
    int e0 = blk * SPAN, e1 = min(E, e0 + SPAN);
    for (int e = e0 + t; e < e1; e += 256) atomicAdd(&cnt[ei[E + e] >> shift], 1);
    __syncthreads();
    for (int b = t; b < NBKT; b += 256)
        if (cnt[b]) atomicAdd(&bcnt[rel * NBKT + b], cnt[b]);
}

// ---------------- pass 2: scan 3*NBKT bucket counts -> starts + cursors --------
__global__ __launch_bounds__(256) void scan_kernel(const int* __restrict__ bcnt,
                                                   int* __restrict__ bstart,
                                                   int* __restrict__ gcur) {
    __shared__ int tsum[256];
    const int M = 3 * NBKT;                 // 4689
    int t = threadIdx.x;
    int vals[19];
    int i0 = t * 19, s = 0;
#pragma unroll
    for (int j = 0; j < 19; ++j) { int i = i0 + j; vals[j] = (i < M) ? bcnt[i] : 0; s += vals[j]; }
    tsum[t] = s;
    __syncthreads();
    for (int d = 1; d < 256; d <<= 1) {
        int v = tsum[t] + ((t >= d) ? tsum[t - d] : 0);
        __syncthreads(); tsum[t] = v; __syncthreads();
    }
    int excl = tsum[t] - s;
#pragma unroll
    for (int j = 0; j < 19; ++j) {
        int i = i0 + j;
        if (i < M) { bstart[i] = excl; gcur[i] = excl; }
        excl += vals[j];
    }
}

// ---------------- pass 3: bucket-grouped scatter into ebuf ---------------------
__global__ __launch_bounds__(256) void scatter_kernel(
    const int* __restrict__ eiC, const int* __restrict__ eiW, const int* __restrict__ eiR,
    int* __restrict__ gcur, unsigned* __restrict__ ebuf, int E, int npart) {
    __shared__ unsigned short stage[SPAN];
    __shared__ int cnt[NBKT];
    __shared__ int lcur[NBKT];
    __shared__ int adj[NBKT];
    __shared__ int tsum[256];
    int rel = blockIdx.x / npart, blk = blockIdx.x % npart;
    const int* ei = rel == 0 ? eiC : (rel == 1 ? eiW : eiR);
    int shift = (rel == 2) ? 6 : 7;
    unsigned dmask = (1u << shift) - 1;
    int t = threadIdx.x;
    int e0 = blk * SPAN, e1 = min(E, e0 + SPAN);
    for (int i = t; i < NBKT; i += 256) cnt[i] = 0;
    __syncthreads();
    for (int e = e0 + t; e < e1; e += 256) atomicAdd(&cnt[ei[E + e] >> shift], 1);
    __syncthreads();
    // local exclusive scan of cnt -> lcur
    int c7[7];
    int i0 = t * 7, s = 0;
#pragma unroll
    for (int j = 0; j < 7; ++j) { int i = i0 + j; c7[j] = (i < NBKT) ? cnt[i] : 0; s += c7[j]; }
    tsum[t] = s;
    __syncthreads();
    for (int d = 1; d < 256; d <<= 1) {
        int v = tsum[t] + ((t >= d) ? tsum[t - d] : 0);
        __syncthreads(); tsum[t] = v; __syncthreads();
    }
    int excl = tsum[t] - s;
#pragma unroll
    for (int j = 0; j < 7; ++j) {
        int i = i0 + j;
        if (i < NBKT) lcur[i] = excl;
        excl += c7[j];
    }
    __syncthreads();
    // claim global ranges; adj[b] = global_base - local_base
#pragma unroll
    for (int j = 0; j < 7; ++j) {
        int i = i0 + j;
        if (i < NBKT) {
            int c = cnt[i];
            adj[i] = c ? (atomicAdd(&gcur[rel * NBKT + i], c) - lcur[i]) : 0;
        }
    }
    __syncthreads();
    // placement: group local edge ids by bucket
    for (int e = e0 + t; e < e1; e += 256) {
        int b = ei[E + e] >> shift;
        int pos = atomicAdd(&lcur[b], 1);
        stage[pos] = (unsigned short)(e - e0);
    }
    __syncthreads();
    // write: consecutive i within a bucket -> consecutive global positions
    int n = e1 - e0;
    for (int i = t; i < n; i += 256) {
        int e = e0 + stage[i];
        int d = ei[E + e], s_ = ei[e];
        int b = d >> shift;
        ebuf[adj[b] + i] = ((unsigned)(d & dmask) << 18) | (unsigned)s_;
    }
}

// ---------------- aggregation helper: lane-per-edge, 2x unrolled ---------------
__device__ __forceinline__ void agg_rows(float* __restrict__ acc, int* __restrict__ cnt,
                                         const __bf16* __restrict__ S,
                                         const unsigned* __restrict__ seg, int n, int t) {
    int e = t;
    for (; e + 256 < n; e += 512) {
        unsigned wA = seg[e], wB = seg[e + 256];
        const bf16x8* rA = (const bf16x8*)(S + (size_t)(wA & SMASK) * 32);
        const bf16x8* rB = (const bf16x8*)(S + (size_t)(wB & SMASK) * 32);
        bf16x8 a0 = rA[0], a1 = rA[1], a2 = rA[2], a3 = rA[3];
        bf16x8 b0 = rB[0], b1 = rB[1], b2 = rB[2], b3 = rB[3];
        float* apA = acc + (wA >> 18) * 33;
        float* apB = acc + (wB >> 18) * 33;
#pragma unroll
        for (int j = 0; j < 8; ++j) {
            unsafeAtomicAdd(apA + j,      (float)a0[j]);
            unsafeAtomicAdd(apA + 8 + j,  (float)a1[j]);
            unsafeAtomicAdd(apA + 16 + j, (float)a2[j]);
            unsafeAtomicAdd(apA + 24 + j, (float)a3[j]);
        }
        atomicAdd(cnt + (wA >> 18), 1);
#pragma unroll
        for (int j = 0; j < 8; ++j) {
            unsafeAtomicAdd(apB + j,      (float)b0[j]);
            unsafeAtomicAdd(apB + 8 + j,  (float)b1[j]);
            unsafeAtomicAdd(apB + 16 + j, (float)b2[j]);
            unsafeAtomicAdd(apB + 24 + j, (float)b3[j]);
        }
        atomicAdd(cnt + (wB >> 18), 1);
    }
    for (; e < n; e += 256) {
        unsigned w = seg[e];
        const bf16x8* r = (const bf16x8*)(S + (size_t)(w & SMASK) * 32);
        bf16x8 a0 = r[0], a1 = r[1], a2 = r[2], a3 = r[3];
        float* ap = acc + (w >> 18) * 33;
#pragma unroll
        for (int j = 0; j < 8; ++j) {
            unsafeAtomicAdd(ap + j,      (float)a0[j]);
            unsafeAtomicAdd(ap + 8 + j,  (float)a1[j]);
            unsafeAtomicAdd(ap + 16 + j, (float)a2[j]);
            unsafeAtomicAdd(ap + 24 + j, (float)a3[j]);
        }
        atomicAdd(cnt + (w >> 18), 1);
    }
}

// ---------------- paper aggregation: one block per 128-node bucket -------------
__global__ __launch_bounds__(256) void agg_paper_kernel(
    const __bf16* __restrict__ YpC, const __bf16* __restrict__ YaW,
    const __bf16* __restrict__ YpD,
    const unsigned* __restrict__ ebuf,
    const int* __restrict__ bstart, const int* __restrict__ bcnt,
    const float* __restrict__ b1l_c, const float* __restrict__ b1l_w,
    const float* __restrict__ uvec,
    float* __restrict__ s_c, float* __restrict__ s_r, int NP) {
    __shared__ float accC[128 * 33];
    __shared__ float accW[128 * 33];
    __shared__ int cntC[128], cntW[128];
    int b = blockIdx.x, t = threadIdx.x;
    for (int i = t; i < 128 * 33; i += 256) { accC[i] = 0.f; accW[i] = 0.f; }
    if (t < 128) { cntC[t] = 0; cntW[t] = 0; }
    __syncthreads();
    agg_rows(accC, cntC, YpC, ebuf + bstart[b], bcnt[b], t);
    agg_rows(accW, cntW, YaW, ebuf + bstart[NBKT + b], bcnt[NBKT + b], t);
    __syncthreads();
    int c = t & 31, nl = t >> 5;
    float bc = b1l_c[c] + b1l_w[c];
    float uc = uvec[c], ur = uvec[64 + c];
#pragma unroll
    for (int k = 0; k < 16; ++k) {
        int n = k * 8 + nl;
        int gn = b * 128 + n;
        if (gn < NP) {
            float mC = accC[n * 33 + c] / (float)max(cntC[n], 1);
            float mW = accW[n * 33 + c] / (float)max(cntW[n], 1);
            float p = fmaxf(mC + mW + (float)YpD[(size_t)gn * 32 + c] + bc, 0.f);
            float vc = p * uc, vr = p * ur;
            for (int m = 1; m < 32; m <<= 1) {
                vc += __shfl_xor(vc, m, 64); vr += __shfl_xor(vr, m, 64);
            }
            if (c == 0) { s_c[gn] = vc; s_r[gn] = vr; }
        }
    }
}

// ---------------- author aggregation: one block per 64-node bucket -------------
__global__ __launch_bounds__(256) void agg_author_kernel(
    const __bf16* __restrict__ YpR, const __bf16* __restrict__ YaD,
    const unsigned* __restrict__ ebuf,
    const int* __restrict__ bstart, const int* __restrict__ bcnt,
    const float* __restrict__ b1l_r, const float* __restrict__ uvec,
    float* __restrict__ s_w, int NA) {
    __shared__ float acc[64 * 33];
    __shared__ int cnt[64];
    int b = blockIdx.x, t = threadIdx.x;
    for (int i = t; i < 64 * 33; i += 256) acc[i] = 0.f;
    if (t < 64) cnt[t] = 0;
    __syncthreads();
    agg_rows(acc, cnt, YpR, ebuf + bstart[2 * NBKT + b], bcnt[2 * NBKT + b], t);
    __syncthreads();
    int c = t & 31, nl = t >> 5;
    float br = b1l_r[c], uw = uvec[32 + c];
#pragma unroll
    for (int k = 0; k < 8; ++k) {
        int n = k * 8 + nl;
        int ga = b * 64 + n;
        if (ga < NA) {
            float mR = acc[n * 33 + c] / (float)max(cnt[n], 1);
            float p = fmaxf(mR + (float)YaD[(size_t)ga * 32 + c] + br, 0.f);
            float vw = p * uw;
            for (int m = 1; m < 32; m <<= 1) vw += __shfl_xor(vw, m, 64);
            if (c == 0) s_w[ga] = vw;
        }
    }
}

// ---------------- layer-2 scalar aggregation + output --------------------------
__global__ __launch_bounds__(256) void out_kernel(
    const float* __restrict__ s_c, const float* __restrict__ s_w,
    const float* __restrict__ s_r,
    const unsigned* __restrict__ ebuf,
    const int* __restrict__ bstart, const int* __restrict__ bcnt,
    const float* __restrict__ uvec, float* __restrict__ out, int NP) {
    __shared__ float aC[128], aW[128];
    __shared__ int cC[128], cW[128];
    int b = blockIdx.x, t = threadIdx.x;
    if (t < 128) { aC[t] = 0.f; aW[t] = 0.f; cC[t] = 0; cW[t] = 0; }
    __syncthreads();
    {
        const unsigned* seg = ebuf + bstart[b];
        int n = bcnt[b];
        int e = t;
        for (; e + 256 < n; e += 512) {
            unsigned wA = seg[e], wB = seg[e + 256];
            float vA = s_c[wA & SMASK], vB = s_c[wB & SMASK];
            unsafeAtomicAdd(&aC[wA >> 18], vA); atomicAdd(&cC[wA >> 18], 1);
            unsafeAtomicAdd(&aC[wB >> 18], vB); atomicAdd(&cC[wB >> 18], 1);
        }
        for (; e < n; e += 256) {
            unsigned w = seg[e];
            unsafeAtomicAdd(&aC[w >> 18], s_c[w & SMASK]); atomicAdd(&cC[w >> 18], 1);
        }
    }
    {
        const unsigned* seg = ebuf + bstart[NBKT + b];
        int n = bcnt[NBKT + b];
        int e = t;
        for (; e + 256 < n; e += 512) {
            unsigned wA = seg[e], wB = seg[e + 256];
            float vA = s_w[wA & SMASK], vB = s_w[wB & SMASK];
            unsafeAtomicAdd(&aW[wA >> 18], vA); atomicAdd(&cW[wA >> 18], 1);
            unsafeAtomicAdd(&aW[wB >> 18], vB); atomicAdd(&cW[wB >> 18], 1);
        }
        for (; e < n; e += 256) {
            unsigned w = seg[e];
            unsafeAtomicAdd(&aW[w >> 18], s_w[w & SMASK]); atomicAdd(&cW[w >> 18], 1);
        }
    }
    __syncthreads();
    if (t < 128) {
        int gn = b * 128 + t;
        if (gn < NP)
            out[gn] = aC[t] / (float)max(cC[t], 1)
                    + aW[t] / (float)max(cW[t], 1) + s_r[gn] + uvec[96];
    }
}

extern "C" void kernel_launch(void* const* d_in, const int* in_sizes, int n_in,
                              void* d_out, int out_size, void* d_ws, size_t ws_size,
                              hipStream_t stream) {
    const float* x_paper  = (const float*)d_in[0];
    const float* x_author = (const float*)d_in[1];
    const int* eiC = (const int*)d_in[2];
    const int* eiW = (const int*)d_in[3];
    const int* eiR = (const int*)d_in[4];
    const float* W1l_c  = (const float*)d_in[5];
    const float* b1l_c  = (const float*)d_in[6];
    const float* W1r_c  = (const float*)d_in[7];
    const float* W1l_w  = (const float*)d_in[8];
    const float* b1l_w  = (const float*)d_in[9];
    const float* W1r_w  = (const float*)d_in[10];
    const float* W1l_r  = (const float*)d_in[11];
    const float* b1l_r  = (const float*)d_in[12];
    const float* W1r_r  = (const float*)d_in[13];
    const float* W2l_c  = (const float*)d_in[14];
    const float* b2l_c  = (const float*)d_in[15];
    const float* W2r_c  = (const float*)d_in[16];
    const float* W2l_w  = (const float*)d_in[17];
    const float* b2l_w  = (const float*)d_in[18];
    const float* W2r_w  = (const float*)d_in[19];
    // d_in[20..22] unused (author layer-2 output not consumed)
    const float* Wh = (const float*)d_in[23];
    const float* bh = (const float*)d_in[24];

    const int NP = in_sizes[0] / 128;
    const int NA = in_sizes[1] / 64;
    const int E  = in_sizes[2] / 2;
    const int npart = (E + SPAN - 1) / SPAN;
    const int NBKp = (NP + 127) >> 7;   // 1563
    const int NBKa = (NA + 63) >> 6;    // 1563

    char* p = (char*)d_ws;
    auto alloc = [&](size_t bytes) -> void* {
        void* r = (void*)p;
        p += (bytes + 255) & ~(size_t)255;
        return r;
    };
    __bf16* YpC = (__bf16*)alloc((size_t)NP * 32 * 2);
    __bf16* YpR = (__bf16*)alloc((size_t)NP * 32 * 2);
    __bf16* YpD = (__bf16*)alloc((size_t)NP * 32 * 2);
    __bf16* YaW = (__bf16*)alloc((size_t)NA * 32 * 2);
    __bf16* YaD = (__bf16*)alloc((size_t)NA * 32 * 2);
    __bf16* Bp_t = (__bf16*)alloc(96 * 128 * 2);
    __bf16* Ba_t = (__bf16*)alloc(64 * 64 * 2);
    float* uvec = (float*)alloc(128 * 4);
    float* s_c  = (float*)alloc((size_t)NP * 4);
    float* s_r  = (float*)alloc((size_t)NP * 4);
    float* s_w  = (float*)alloc((size_t)NA * 4);
    int* bcnt   = (int*)alloc((size_t)3 * NBKT * 4);
    int* bstart = (int*)alloc((size_t)3 * NBKT * 4);
    int* gcur   = (int*)alloc((size_t)3 * NBKT * 4);
    unsigned* ebuf = (unsigned*)alloc((size_t)3 * E * 4);   // 12 MB

    hipMemsetAsync(bcnt, 0, (size_t)3 * NBKT * 4, stream);

    prep_kernel<<<1, 256, 0, stream>>>(W1l_c, W1l_r, W1r_c, W1r_w, W1l_w, W1r_r,
                                       W2l_c, W2l_w, W2r_c, W2r_w, b2l_c, b2l_w,
                                       Wh, bh, Bp_t, Ba_t, uvec);

    proj_kernel<128, 3><<<(NP + 63) / 64, 256, 0, stream>>>(x_paper, Bp_t, YpC, YpR, YpD, NP);
    proj_kernel<64, 2><<<(NA + 63) / 64, 256, 0, stream>>>(x_author, Ba_t, YaW, YaD, nullptr, NA);

    hist_kernel<<<3 * npart, 256, 0, stream>>>(eiC, eiW, eiR, bcnt, E, npart);
    scan_kernel<<<1, 256, 0, stream>>>(bcnt, bstart, gcur);
    scatter_kernel<<<3 * npart, 256, 0, stream>>>(eiC, eiW, eiR, gcur, ebuf, E, npart);

    agg_paper_kernel<<<NBKp, 256, 0, stream>>>(YpC, YaW, YpD, ebuf, bstart, bcnt,
                                               b1l_c, b1l_w, uvec, s_c, s_r, NP);
    agg_author_kernel<<<NBKa, 256, 0, stream>>>(YpR, YaD, ebuf, bstart, bcnt,
                                                b1l_r, uvec, s_w, NA);
    out_kernel<<<NBKp, 256, 0, stream>>>(s_c, s_w, s_r, ebuf, bstart, bcnt,
                                         uvec, (float*)d_out, NP);
}

// Round 6
// 502.705 us; speedup vs baseline: 2.0833x; 1.9072x over previous
//
#include <hip/hip_runtime.h>
#include <hip/hip_bf16.h>

// HeteroSAGE collapsed pipeline (float32 I/O, bf16 MFMA + bf16 intermediates):
//   out[i] = mean_cites(s_c[src]) + mean_writes(s_w[src]) + s_r[i] + C0
//   s_c = p1.(W2l_c@Wh), s_r = p1.((W2r_c+W2r_w)@Wh), s_w = a1.(W2l_w@Wh)
//   p1 = relu(mean_c(YpC[src]) + mean_w(YaW[src]) + YpD + b1c + b1w)
//   a1 = relu(mean_r(YpR[src]) + YaD + b1rev)
// Round-6: rounds 3/4/5 all pinned at ~400us in aggregation regardless of edge
// layout -> per-edge scattered LDS atomics (via generic pointers) were the
// invariant cost. Now edges are sorted to EXACT dst order (bucket pass + in-bucket
// 128-way counting sort), and aggregation is pure register accumulation:
// half-wave (32 ch) per node, one coalesced 64B line per edge, no atomics.

#define SPAN  8192
#define NBKT  1563        // ceil(200000/128) == ceil(100000/64)
#define SMASK 0x3FFFF     // 18-bit src index (200000 < 2^18)

typedef __bf16 bf16x8 __attribute__((ext_vector_type(8)));
typedef float f32x4 __attribute__((ext_vector_type(4)));

// ---------------- prep: combined transposed weights (f32 -> bf16) + head vecs --
__global__ void prep_kernel(const float* W1l_c, const float* W1l_rev,
                            const float* W1r_c, const float* W1r_w,
                            const float* W1l_w, const float* W1r_rev,
                            const float* W2l_c, const float* W2l_w,
                            const float* W2r_c, const float* W2r_w,
                            const float* b2l_c, const float* b2l_w,
                            const float* Wh, const float* bh,
                            __bf16* Bp_t, __bf16* Ba_t, float* uvec) {
    int t = threadIdx.x;
    for (int idx = t; idx < 96 * 128; idx += 256) {   // Bp_t[n][k] n<96,k<128
        int n = idx >> 7, k = idx & 127;
        float v;
        if (n < 32)      v = W1l_c[k * 32 + n];
        else if (n < 64) v = W1l_rev[k * 32 + (n - 32)];
        else             v = W1r_c[k * 32 + (n - 64)] + W1r_w[k * 32 + (n - 64)];
        Bp_t[n * 128 + k] = (__bf16)v;
    }
    for (int idx = t; idx < 64 * 64; idx += 256) {    // Ba_t[n][k] n<64,k<64
        int n = idx >> 6, k = idx & 63;
        float v = (n < 32) ? W1l_w[k * 32 + n] : W1r_rev[k * 32 + (n - 32)];
        Ba_t[n * 64 + k] = (__bf16)v;
    }
    if (t < 32) {
        float uc = 0.f, uw = 0.f, ur = 0.f;
        for (int j = 0; j < 32; ++j) {
            float wh = Wh[j];
            uc += W2l_c[t * 32 + j] * wh;
            uw += W2l_w[t * 32 + j] * wh;
            ur += (W2r_c[t * 32 + j] + W2r_w[t * 32 + j]) * wh;
        }
        uvec[t] = uc; uvec[32 + t] = uw; uvec[64 + t] = ur;
        if (t == 0) {
            float c0 = bh[0];
            for (int j = 0; j < 32; ++j) c0 += (b2l_c[j] + b2l_w[j]) * Wh[j];
            uvec[96] = c0;
        }
    }
}

// ---------------- projection GEMM: split 32-col groups to separate arrays ------
template <int K, int NG>
__global__ __launch_bounds__(256) void proj_kernel(const float* __restrict__ X,
                                                   const __bf16* __restrict__ Bt,
                                                   __bf16* __restrict__ D0,
                                                   __bf16* __restrict__ D1,
                                                   __bf16* __restrict__ D2, int M) {
    constexpr int NT = NG * 2, KT = K / 32;
    int lane = threadIdx.x & 63;
    int wave = (blockIdx.x * 256 + threadIdx.x) >> 6;
    int m0 = wave * 16;
    if (m0 + 16 > M) return;  // M % 16 == 0 here
    int lr = lane & 15;
    int quad = lane >> 4;

    bf16x8 bfrag[NT][KT];
#pragma unroll
    for (int ct = 0; ct < NT; ++ct)
#pragma unroll
        for (int ks = 0; ks < KT; ++ks)
            bfrag[ct][ks] = *(const bf16x8*)(Bt + (ct * 16 + lr) * K + ks * 32 + quad * 8);

    bf16x8 afrag[KT];
    const float* xrow = X + (size_t)(m0 + lr) * K + quad * 8;
#pragma unroll
    for (int ks = 0; ks < KT; ++ks) {
        f32x4 lo = *(const f32x4*)(xrow + ks * 32);
        f32x4 hi = *(const f32x4*)(xrow + ks * 32 + 4);
        bf16x8 a;
#pragma unroll
        for (int j = 0; j < 4; ++j) { a[j] = (__bf16)lo[j]; a[4 + j] = (__bf16)hi[j]; }
        afrag[ks] = a;
    }

#pragma unroll
    for (int ct = 0; ct < NT; ++ct) {
        f32x4 acc = {0.f, 0.f, 0.f, 0.f};
#pragma unroll
        for (int ks = 0; ks < KT; ++ks)
            acc = __builtin_amdgcn_mfma_f32_16x16x32_bf16(afrag[ks], bfrag[ct][ks], acc, 0, 0, 0);
        __bf16* D = ((ct >> 1) == 0) ? D0 : (((ct >> 1) == 1) ? D1 : D2);
        int col = (ct & 1) * 16 + lr;
        int rbase = m0 + quad * 4;
#pragma unroll
        for (int r = 0; r < 4; ++r)
            D[(size_t)(rbase + r) * 32 + col] = (__bf16)acc[r];
    }
}

// ---------------- pass 1: per-span LDS histogram -> global bucket counts -------
__global__ __launch_bounds__(256) void hist_kernel(
    const int* __restrict__ eiC, const int* __restrict__ eiW, const int* __restrict__ eiR,
    int* __restrict__ bcnt, int E, int npart) {
    __shared__ int cnt[NBKT];
    int rel = blockIdx.x / npart, blk = blockIdx.x % npart;
    const int* ei = rel == 0 ? eiC : (rel == 1 ? eiW : eiR);
    int shift = (rel == 2) ? 6 : 7;
    int t = threadIdx.x;
    for (int i = t; i < NBKT; i += 256) cnt[i] = 0;
    __syncthreads();
    int e0 = blk * SPAN, e1 = min(E, e0 + SPAN);
    for (int e = e0 + t; e < e1; e += 256) atomicAdd(&cnt[ei[E + e] >> shift], 1);
    __syncthreads();
    for (int b = t; b < NBKT; b += 256)
        if (cnt[b]) atomicAdd(&bcnt[rel * NBKT + b], cnt[b]);
}

// ---------------- pass 2: scan 3*NBKT bucket counts -> starts + cursors --------
__global__ __launch_bounds__(256) void scan_kernel(const int* __restrict__ bcnt,
                                                   int* __restrict__ bstart,
                                                   int* __restrict__ gcur) {
    __shared__ int tsum[256];
    const int M = 3 * NBKT;                 // 4689
    int t = threadIdx.x;
    int vals[19];
    int i0 = t * 19, s = 0;
#pragma unroll
    for (int j = 0; j < 19; ++j) { int i = i0 + j; vals[j] = (i < M) ? bcnt[i] : 0; s += vals[j]; }
    tsum[t] = s;
    __syncthreads();
    for (int d = 1; d < 256; d <<= 1) {
        int v = tsum[t] + ((t >= d) ? tsum[t - d] : 0);
        __syncthreads(); tsum[t] = v; __syncthreads();
    }
    int excl = tsum[t] - s;
#pragma unroll
    for (int j = 0; j < 19; ++j) {
        int i = i0 + j;
        if (i < M) { bstart[i] = excl; gcur[i] = excl; }
        excl += vals[j];
    }
}

// ---------------- pass 3: bucket-grouped scatter into ebuf ---------------------
__global__ __launch_bounds__(256) void scatter_kernel(
    const int* __restrict__ eiC, const int* __restrict__ eiW, const int* __restrict__ eiR,
    int* __restrict__ gcur, unsigned* __restrict__ ebuf, int E, int npart) {
    __shared__ unsigned short stage[SPAN];
    __shared__ int cnt[NBKT];
    __shared__ int lcur[NBKT];
    __shared__ int adj[NBKT];
    __shared__ int tsum[256];
    int rel = blockIdx.x / npart, blk = blockIdx.x % npart;
    const int* ei = rel == 0 ? eiC : (rel == 1 ? eiW : eiR);
    int shift = (rel == 2) ? 6 : 7;
    unsigned dmask = (1u << shift) - 1;
    int t = threadIdx.x;
    int e0 = blk * SPAN, e1 = min(E, e0 + SPAN);
    for (int i = t; i < NBKT; i += 256) cnt[i] = 0;
    __syncthreads();
    for (int e = e0 + t; e < e1; e += 256) atomicAdd(&cnt[ei[E + e] >> shift], 1);
    __syncthreads();
    // local exclusive scan of cnt -> lcur
    int c7[7];
    int i0 = t * 7, s = 0;
#pragma unroll
    for (int j = 0; j < 7; ++j) { int i = i0 + j; c7[j] = (i < NBKT) ? cnt[i] : 0; s += c7[j]; }
    tsum[t] = s;
    __syncthreads();
    for (int d = 1; d < 256; d <<= 1) {
        int v = tsum[t] + ((t >= d) ? tsum[t - d] : 0);
        __syncthreads(); tsum[t] = v; __syncthreads();
    }
    int excl = tsum[t] - s;
#pragma unroll
    for (int j = 0; j < 7; ++j) {
        int i = i0 + j;
        if (i < NBKT) lcur[i] = excl;
        excl += c7[j];
    }
    __syncthreads();
    // claim global ranges; adj[b] = global_base - local_base
#pragma unroll
    for (int j = 0; j < 7; ++j) {
        int i = i0 + j;
        if (i < NBKT) {
            int c = cnt[i];
            adj[i] = c ? (atomicAdd(&gcur[rel * NBKT + i], c) - lcur[i]) : 0;
        }
    }
    __syncthreads();
    // placement: group local edge ids by bucket
    for (int e = e0 + t; e < e1; e += 256) {
        int b = ei[E + e] >> shift;
        int pos = atomicAdd(&lcur[b], 1);
        stage[pos] = (unsigned short)(e - e0);
    }
    __syncthreads();
    // write: consecutive i within a bucket -> consecutive global positions
    int n = e1 - e0;
    for (int i = t; i < n; i += 256) {
        int e = e0 + stage[i];
        int d = ei[E + e], s_ = ei[e];
        int b = d >> shift;
        ebuf[adj[b] + i] = ((unsigned)(d & dmask) << 18) | (unsigned)s_;
    }
}

// ---------------- pass 4: in-bucket counting sort by exact dst (in-place) ------
// After this, ebuf[bstart[idx] .. +n) holds PLAIN SRC indices sorted by dst, and
// nstart/ncnt give each node's segment. Node spaces: [0,NPS) cites->paper,
// [NPS,2*NPS) writes->paper, [2*NPS, 2*NPS+NAS) rev->author.
__global__ __launch_bounds__(256) void sort_kernel(
    unsigned* __restrict__ ebuf, const int* __restrict__ bstart,
    const int* __restrict__ bcnt, int* __restrict__ nstart, int* __restrict__ ncnt) {
    __shared__ unsigned stage[2048];
    __shared__ int cnt[128], exc[128], cur[128];
    int idx = blockIdx.x;             // [0, 3*NBKT)
    int rel = idx / NBKT, b = idx % NBKT;
    int nodes = (rel == 2) ? 64 : 128;
    int t = threadIdx.x;
    int start = bstart[idx];
    int n = min(bcnt[idx], 2048);     // Poisson(640) max ~800; 2048 = safety
    if (t < 128) cnt[t] = 0;
    __syncthreads();
    for (int i = t; i < n; i += 256) atomicAdd(&cnt[ebuf[start + i] >> 18], 1);
    __syncthreads();
    if (t < 128) exc[t] = cnt[t];
    __syncthreads();
    for (int d = 1; d < 128; d <<= 1) {
        int v = 0;
        if (t < 128) v = exc[t] + ((t >= d) ? exc[t - d] : 0);
        __syncthreads();
        if (t < 128) exc[t] = v;
        __syncthreads();
    }
    if (t < 128) { int e = exc[t] - cnt[t]; exc[t] = e; cur[t] = e; }
    __syncthreads();
    for (int i = t; i < n; i += 256) {
        unsigned w = ebuf[start + i];
        int pos = atomicAdd(&cur[w >> 18], 1);
        stage[pos] = w & SMASK;
    }
    __syncthreads();
    for (int i = t; i < n; i += 256) ebuf[start + i] = stage[i];
    int nbase = (rel == 0) ? b * 128
              : (rel == 1) ? NBKT * 128 + b * 128
                           : 2 * NBKT * 128 + b * 64;
    if (t < nodes) { nstart[nbase + t] = start + exc[t]; ncnt[nbase + t] = cnt[t]; }
}

// ---------------- paper aggregation: half-wave per node, register accumulate ---
__global__ __launch_bounds__(256) void agg_paper_kernel(
    const __bf16* __restrict__ YpC, const __bf16* __restrict__ YaW,
    const __bf16* __restrict__ YpD, const unsigned* __restrict__ ebuf,
    const int* __restrict__ nstart, const int* __restrict__ ncnt,
    const float* __restrict__ b1l_c, const float* __restrict__ b1l_w,
    const float* __restrict__ uvec,
    float* __restrict__ s_c, float* __restrict__ s_r, int NP) {
    int gn = (blockIdx.x * 256 + threadIdx.x) >> 5;
    int c = threadIdx.x & 31;
    if (gn >= NP) return;
    const int NPS = NBKT * 128;
    float aC = 0.f, aW = 0.f;
    {
        int o = nstart[gn], n = ncnt[gn];
        int e = 0;
        for (; e + 4 <= n; e += 4) {
            int s0 = ebuf[o + e], s1 = ebuf[o + e + 1];
            int s2 = ebuf[o + e + 2], s3 = ebuf[o + e + 3];
            aC += (float)YpC[(size_t)s0 * 32 + c] + (float)YpC[(size_t)s1 * 32 + c]
                + (float)YpC[(size_t)s2 * 32 + c] + (float)YpC[(size_t)s3 * 32 + c];
        }
        for (; e < n; ++e) aC += (float)YpC[(size_t)ebuf[o + e] * 32 + c];
        aC /= (float)max(n, 1);
    }
    {
        int o = nstart[NPS + gn], n = ncnt[NPS + gn];
        int e = 0;
        for (; e + 4 <= n; e += 4) {
            int s0 = ebuf[o + e], s1 = ebuf[o + e + 1];
            int s2 = ebuf[o + e + 2], s3 = ebuf[o + e + 3];
            aW += (float)YaW[(size_t)s0 * 32 + c] + (float)YaW[(size_t)s1 * 32 + c]
                + (float)YaW[(size_t)s2 * 32 + c] + (float)YaW[(size_t)s3 * 32 + c];
        }
        for (; e < n; ++e) aW += (float)YaW[(size_t)ebuf[o + e] * 32 + c];
        aW /= (float)max(n, 1);
    }
    float p = aC + aW + (float)YpD[(size_t)gn * 32 + c] + b1l_c[c] + b1l_w[c];
    p = fmaxf(p, 0.f);
    float vc = p * uvec[c], vr = p * uvec[64 + c];
    for (int m = 1; m < 32; m <<= 1) { vc += __shfl_xor(vc, m, 64); vr += __shfl_xor(vr, m, 64); }
    if (c == 0) { s_c[gn] = vc; s_r[gn] = vr; }
}

// ---------------- author aggregation ------------------------------------------
__global__ __launch_bounds__(256) void agg_author_kernel(
    const __bf16* __restrict__ YpR, const __bf16* __restrict__ YaD,
    const unsigned* __restrict__ ebuf,
    const int* __restrict__ nstart, const int* __restrict__ ncnt,
    const float* __restrict__ b1l_r, const float* __restrict__ uvec,
    float* __restrict__ s_w, int NA) {
    int ga = (blockIdx.x * 256 + threadIdx.x) >> 5;
    int c = threadIdx.x & 31;
    if (ga >= NA) return;
    const int base = 2 * NBKT * 128;
    float aR = 0.f;
    int o = nstart[base + ga], n = ncnt[base + ga];
    int e = 0;
    for (; e + 4 <= n; e += 4) {
        int s0 = ebuf[o + e], s1 = ebuf[o + e + 1];
        int s2 = ebuf[o + e + 2], s3 = ebuf[o + e + 3];
        aR += (float)YpR[(size_t)s0 * 32 + c] + (float)YpR[(size_t)s1 * 32 + c]
            + (float)YpR[(size_t)s2 * 32 + c] + (float)YpR[(size_t)s3 * 32 + c];
    }
    for (; e < n; ++e) aR += (float)YpR[(size_t)ebuf[o + e] * 32 + c];
    float p = aR / (float)max(n, 1) + (float)YaD[(size_t)ga * 32 + c] + b1l_r[c];
    p = fmaxf(p, 0.f);
    float vw = p * uvec[32 + c];
    for (int m = 1; m < 32; m <<= 1) vw += __shfl_xor(vw, m, 64);
    if (c == 0) s_w[ga] = vw;
}

// ---------------- layer-2 scalar aggregation + output: lane per node -----------
__global__ __launch_bounds__(256) void out_kernel(
    const float* __restrict__ s_c, const float* __restrict__ s_w,
    const float* __restrict__ s_r, const unsigned* __restrict__ ebuf,
    const int* __restrict__ nstart, const int* __restrict__ ncnt,
    const float* __restrict__ uvec, float* __restrict__ out, int NP) {
    int gn = blockIdx.x * 256 + threadIdx.x;
    if (gn >= NP) return;
    const int NPS = NBKT * 128;
    int o = nstart[gn], n = ncnt[gn];
    float sC = 0.f;
    for (int e = 0; e < n; ++e) sC += s_c[ebuf[o + e]];
    int o2 = nstart[NPS + gn], n2 = ncnt[NPS + gn];
    float sW = 0.f;
    for (int e = 0; e < n2; ++e) sW += s_w[ebuf[o2 + e]];
    out[gn] = sC / (float)max(n, 1) + sW / (float)max(n2, 1) + s_r[gn] + uvec[96];
}

extern "C" void kernel_launch(void* const* d_in, const int* in_sizes, int n_in,
                              void* d_out, int out_size, void* d_ws, size_t ws_size,
                              hipStream_t stream) {
    const float* x_paper  = (const float*)d_in[0];
    const float* x_author = (const float*)d_in[1];
    const int* eiC = (const int*)d_in[2];
    const int* eiW = (const int*)d_in[3];
    const int* eiR = (const int*)d_in[4];
    const float* W1l_c  = (const float*)d_in[5];
    const float* b1l_c  = (const float*)d_in[6];
    const float* W1r_c  = (const float*)d_in[7];
    const float* W1l_w  = (const float*)d_in[8];
    const float* b1l_w  = (const float*)d_in[9];
    const float* W1r_w  = (const float*)d_in[10];
    const float* W1l_r  = (const float*)d_in[11];
    const float* b1l_r  = (const float*)d_in[12];
    const float* W1r_r  = (const float*)d_in[13];
    const float* W2l_c  = (const float*)d_in[14];
    const float* b2l_c  = (const float*)d_in[15];
    const float* W2r_c  = (const float*)d_in[16];
    const float* W2l_w  = (const float*)d_in[17];
    const float* b2l_w  = (const float*)d_in[18];
    const float* W2r_w  = (const float*)d_in[19];
    // d_in[20..22] unused (author layer-2 output not consumed)
    const float* Wh = (const float*)d_in[23];
    const float* bh = (const float*)d_in[24];

    const int NP = in_sizes[0] / 128;
    const int NA = in_sizes[1] / 64;
    const int E  = in_sizes[2] / 2;
    const int npart = (E + SPAN - 1) / SPAN;
    const int NNODE = NBKT * 128 * 2 + NBKT * 64;   // cites|writes|rev node spaces

    char* p = (char*)d_ws;
    auto alloc = [&](size_t bytes) -> void* {
        void* r = (void*)p;
        p += (bytes + 255) & ~(size_t)255;
        return r;
    };
    __bf16* YpC = (__bf16*)alloc((size_t)NP * 32 * 2);
    __bf16* YpR = (__bf16*)alloc((size_t)NP * 32 * 2);
    __bf16* YpD = (__bf16*)alloc((size_t)NP * 32 * 2);
    __bf16* YaW = (__bf16*)alloc((size_t)NA * 32 * 2);
    __bf16* YaD = (__bf16*)alloc((size_t)NA * 32 * 2);
    __bf16* Bp_t = (__bf16*)alloc(96 * 128 * 2);
    __bf16* Ba_t = (__bf16*)alloc(64 * 64 * 2);
    float* uvec = (float*)alloc(128 * 4);
    float* s_c  = (float*)alloc((size_t)NP * 4);
    float* s_r  = (float*)alloc((size_t)NP * 4);
    float* s_w  = (float*)alloc((size_t)NA * 4);
    int* bcnt   = (int*)alloc((size_t)3 * NBKT * 4);
    int* bstart = (int*)alloc((size_t)3 * NBKT * 4);
    int* gcur   = (int*)alloc((size_t)3 * NBKT * 4);
    int* nstart = (int*)alloc((size_t)NNODE * 4);
    int* ncnt   = (int*)alloc((size_t)NNODE * 4);
    unsigned* ebuf = (unsigned*)alloc((size_t)3 * E * 4);   // 12 MB

    hipMemsetAsync(bcnt, 0, (size_t)3 * NBKT * 4, stream);

    prep_kernel<<<1, 256, 0, stream>>>(W1l_c, W1l_r, W1r_c, W1r_w, W1l_w, W1r_r,
                                       W2l_c, W2l_w, W2r_c, W2r_w, b2l_c, b2l_w,
                                       Wh, bh, Bp_t, Ba_t, uvec);

    proj_kernel<128, 3><<<(NP + 63) / 64, 256, 0, stream>>>(x_paper, Bp_t, YpC, YpR, YpD, NP);
    proj_kernel<64, 2><<<(NA + 63) / 64, 256, 0, stream>>>(x_author, Ba_t, YaW, YaD, nullptr, NA);

    hist_kernel<<<3 * npart, 256, 0, stream>>>(eiC, eiW, eiR, bcnt, E, npart);
    scan_kernel<<<1, 256, 0, stream>>>(bcnt, bstart, gcur);
    scatter_kernel<<<3 * npart, 256, 0, stream>>>(eiC, eiW, eiR, gcur, ebuf, E, npart);
    sort_kernel<<<3 * NBKT, 256, 0, stream>>>(ebuf, bstart, bcnt, nstart, ncnt);

    agg_paper_kernel<<<(NP * 32 + 255) / 256, 256, 0, stream>>>(
        YpC, YaW, YpD, ebuf, nstart, ncnt, b1l_c, b1l_w, uvec, s_c, s_r, NP);
    agg_author_kernel<<<(NA * 32 + 255) / 256, 256, 0, stream>>>(
        YpR, YaD, ebuf, nstart, ncnt, b1l_r, uvec, s_w, NA);
    out_kernel<<<(NP + 255) / 256, 256, 0, stream>>>(
        s_c, s_w, s_r, ebuf, nstart, ncnt, uvec, (float*)d_out, NP);
}

// Round 7
// 482.932 us; speedup vs baseline: 2.1686x; 1.0409x over previous
//
#include <hip/hip_runtime.h>
#include <hip/hip_bf16.h>

// HeteroSAGE collapsed pipeline (float32 I/O, bf16 MFMA + bf16 intermediates):
//   out[i] = mean_cites(s_c[src]) + mean_writes(s_w[src]) + s_r[i] + C0
//   s_c = p1.(W2l_c@Wh), s_r = p1.((W2r_c+W2r_w)@Wh), s_w = a1.(W2l_w@Wh)
//   p1 = relu(mean_c(YpC[src]) + mean_w(YaW[src]) + YpD + b1c + b1w)
//   a1 = relu(mean_r(YpR[src]) + YaD + b1rev)
// R6 lesson: dst-sorted edges + register accumulation = 83us agg (was 400us with
// LDS atomics). R7: (1) padded bucket regions kill hist+scan passes, (2) proj+
// scatter fused into one kernel (independent roles overlap on the CUs), (3) agg
// unified paper+author with bf16x2 16-lane subgroups for 2x lines-in-flight.

#define SPAN  8192
#define NBKT  1563        // ceil(200000/128) == ceil(100000/64)
#define CAP   1024        // padded region per (rel,bucket); Poisson(640), 15 sigma
#define SMASK 0x3FFFF     // 18-bit src index (200000 < 2^18)

typedef __bf16 bf16x8 __attribute__((ext_vector_type(8)));
typedef __bf16 bf16x2 __attribute__((ext_vector_type(2)));
typedef float f32x4 __attribute__((ext_vector_type(4)));

// ---------------- prep: weights -> bf16, head vecs, cursor init ----------------
__global__ void prep_kernel(const float* W1l_c, const float* W1l_rev,
                            const float* W1r_c, const float* W1r_w,
                            const float* W1l_w, const float* W1r_rev,
                            const float* W2l_c, const float* W2l_w,
                            const float* W2r_c, const float* W2r_w,
                            const float* b2l_c, const float* b2l_w,
                            const float* Wh, const float* bh,
                            __bf16* Bp_t, __bf16* Ba_t, float* uvec, int* gcur) {
    int t = threadIdx.x;
    for (int i = t; i < 3 * NBKT; i += 256) gcur[i] = i << 10;   // padded bases
    for (int idx = t; idx < 96 * 128; idx += 256) {   // Bp_t[n][k] n<96,k<128
        int n = idx >> 7, k = idx & 127;
        float v;
        if (n < 32)      v = W1l_c[k * 32 + n];
        else if (n < 64) v = W1l_rev[k * 32 + (n - 32)];
        else             v = W1r_c[k * 32 + (n - 64)] + W1r_w[k * 32 + (n - 64)];
        Bp_t[n * 128 + k] = (__bf16)v;
    }
    for (int idx = t; idx < 64 * 64; idx += 256) {    // Ba_t[n][k] n<64,k<64
        int n = idx >> 6, k = idx & 63;
        float v = (n < 32) ? W1l_w[k * 32 + n] : W1r_rev[k * 32 + (n - 32)];
        Ba_t[n * 64 + k] = (__bf16)v;
    }
    if (t < 32) {
        float uc = 0.f, uw = 0.f, ur = 0.f;
        for (int j = 0; j < 32; ++j) {
            float wh = Wh[j];
            uc += W2l_c[t * 32 + j] * wh;
            uw += W2l_w[t * 32 + j] * wh;
            ur += (W2r_c[t * 32 + j] + W2r_w[t * 32 + j]) * wh;
        }
        uvec[t] = uc; uvec[32 + t] = uw; uvec[64 + t] = ur;
        if (t == 0) {
            float c0 = bh[0];
            for (int j = 0; j < 32; ++j) c0 += (b2l_c[j] + b2l_w[j]) * Wh[j];
            uvec[96] = c0;
        }
    }
}

// ---------------- proj body (MFMA 16x16x32 bf16), 32-col group split -----------
template <int K, int NG>
__device__ __forceinline__ void proj_body(const float* __restrict__ X,
                                          const __bf16* __restrict__ Bt,
                                          __bf16* __restrict__ D0,
                                          __bf16* __restrict__ D1,
                                          __bf16* __restrict__ D2, int M, int bid) {
    constexpr int NT = NG * 2, KT = K / 32;
    int lane = threadIdx.x & 63;
    int wave = (bid * 256 + (int)threadIdx.x) >> 6;
    int m0 = wave * 16;
    if (m0 + 16 > M) return;  // M % 16 == 0 here
    int lr = lane & 15;
    int quad = lane >> 4;

    bf16x8 bfrag[NT][KT];
#pragma unroll
    for (int ct = 0; ct < NT; ++ct)
#pragma unroll
        for (int ks = 0; ks < KT; ++ks)
            bfrag[ct][ks] = *(const bf16x8*)(Bt + (ct * 16 + lr) * K + ks * 32 + quad * 8);

    bf16x8 afrag[KT];
    const float* xrow = X + (size_t)(m0 + lr) * K + quad * 8;
#pragma unroll
    for (int ks = 0; ks < KT; ++ks) {
        f32x4 lo = *(const f32x4*)(xrow + ks * 32);
        f32x4 hi = *(const f32x4*)(xrow + ks * 32 + 4);
        bf16x8 a;
#pragma unroll
        for (int j = 0; j < 4; ++j) { a[j] = (__bf16)lo[j]; a[4 + j] = (__bf16)hi[j]; }
        afrag[ks] = a;
    }

#pragma unroll
    for (int ct = 0; ct < NT; ++ct) {
        f32x4 acc = {0.f, 0.f, 0.f, 0.f};
#pragma unroll
        for (int ks = 0; ks < KT; ++ks)
            acc = __builtin_amdgcn_mfma_f32_16x16x32_bf16(afrag[ks], bfrag[ct][ks], acc, 0, 0, 0);
        __bf16* D = ((ct >> 1) == 0) ? D0 : (((ct >> 1) == 1) ? D1 : D2);
        int col = (ct & 1) * 16 + lr;
        int rbase = m0 + quad * 4;
#pragma unroll
        for (int r = 0; r < 4; ++r)
            D[(size_t)(rbase + r) * 32 + col] = (__bf16)acc[r];
    }
}

// ---------------- scatter body: span -> per-bucket runs in padded regions ------
__device__ void scatter_body(const int* __restrict__ eiC, const int* __restrict__ eiW,
                             const int* __restrict__ eiR, int* __restrict__ gcur,
                             unsigned* __restrict__ ebuf, int E, int npart, int bid,
                             unsigned short* stage, int* cnt, int* lcur, int* adj,
                             int* tsum) {
    int rel = bid / npart, blk = bid % npart;
    const int* ei = rel == 0 ? eiC : (rel == 1 ? eiW : eiR);
    int shift = (rel == 2) ? 6 : 7;
    unsigned dmask = (1u << shift) - 1;
    int t = threadIdx.x;
    int e0 = blk * SPAN, e1 = min(E, e0 + SPAN);
    for (int i = t; i < NBKT; i += 256) cnt[i] = 0;
    __syncthreads();
    for (int e = e0 + t; e < e1; e += 256) atomicAdd(&cnt[ei[E + e] >> shift], 1);
    __syncthreads();
    // local exclusive scan of cnt -> lcur
    int c7[7];
    int i0 = t * 7, s = 0;
#pragma unroll
    for (int j = 0; j < 7; ++j) { int i = i0 + j; c7[j] = (i < NBKT) ? cnt[i] : 0; s += c7[j]; }
    tsum[t] = s;
    __syncthreads();
    for (int d = 1; d < 256; d <<= 1) {
        int v = tsum[t] + ((t >= d) ? tsum[t - d] : 0);
        __syncthreads(); tsum[t] = v; __syncthreads();
    }
    int excl = tsum[t] - s;
#pragma unroll
    for (int j = 0; j < 7; ++j) {
        int i = i0 + j;
        if (i < NBKT) lcur[i] = excl;
        excl += c7[j];
    }
    __syncthreads();
    // claim global runs in padded bucket regions
#pragma unroll
    for (int j = 0; j < 7; ++j) {
        int i = i0 + j;
        if (i < NBKT) {
            int c = c7[j];
            adj[i] = c ? (atomicAdd(&gcur[rel * NBKT + i], c) - lcur[i]) : 0;
        }
    }
    __syncthreads();
    // group local edge ids by bucket
    for (int e = e0 + t; e < e1; e += 256) {
        int b = ei[E + e] >> shift;
        int pos = atomicAdd(&lcur[b], 1);
        stage[pos] = (unsigned short)(e - e0);
    }
    __syncthreads();
    // write runs (consecutive i within bucket -> consecutive global positions)
    int n = e1 - e0;
    for (int i = t; i < n; i += 256) {
        int e = e0 + stage[i];
        int d = ei[E + e], s_ = ei[e];
        int b = d >> shift;
        int gpos = adj[b] + i;
        if (gpos < (((rel * NBKT + b) + 1) << 10))   // capacity clamp (~never)
            ebuf[gpos] = ((unsigned)(d & dmask) << 18) | (unsigned)s_;
    }
}

// ---------------- mid: proj_paper | proj_author | scatter (fused, overlap) -----
__global__ __launch_bounds__(256) void mid_kernel(
    const float* __restrict__ Xp, const float* __restrict__ Xa,
    const __bf16* __restrict__ Bp_t, const __bf16* __restrict__ Ba_t,
    __bf16* __restrict__ YpC, __bf16* __restrict__ YpR, __bf16* __restrict__ YpD,
    __bf16* __restrict__ YaW, __bf16* __restrict__ YaD,
    const int* __restrict__ eiC, const int* __restrict__ eiW,
    const int* __restrict__ eiR, int* __restrict__ gcur,
    unsigned* __restrict__ ebuf, int NP, int NA, int E,
    int nPp, int nPa, int npart) {
    __shared__ unsigned short stage[SPAN];
    __shared__ int cnt[NBKT];
    __shared__ int lcur[NBKT];
    __shared__ int adj[NBKT];
    __shared__ int tsum[256];
    int bid = blockIdx.x;
    if (bid < nPp) { proj_body<128, 3>(Xp, Bp_t, YpC, YpR, YpD, NP, bid); return; }
    bid -= nPp;
    if (bid < nPa) { proj_body<64, 2>(Xa, Ba_t, YaW, YaD, nullptr, NA, bid); return; }
    bid -= nPa;
    scatter_body(eiC, eiW, eiR, gcur, ebuf, E, npart, bid, stage, cnt, lcur, adj, tsum);
}

// ---------------- sort: in-bucket counting sort by exact dst (in-place) --------
// ebuf[bucket region] -> plain src indices sorted by dst; nstart/ncnt per node.
__global__ __launch_bounds__(256) void sort_kernel(
    unsigned* __restrict__ ebuf, const int* __restrict__ gcur,
    int* __restrict__ nstart, int* __restrict__ ncnt) {
    __shared__ unsigned stage[CAP];
    __shared__ int cnt[128], exc[128], cur[128];
    int idx = blockIdx.x;             // [0, 3*NBKT)
    int rel = idx / NBKT, b = idx % NBKT;
    int nodes = (rel == 2) ? 64 : 128;
    int t = threadIdx.x;
    int start = idx << 10;
    int n = min(gcur[idx] - start, CAP);
    if (t < 128) cnt[t] = 0;
    __syncthreads();
    for (int i = t; i < n; i += 256) atomicAdd(&cnt[ebuf[start + i] >> 18], 1);
    __syncthreads();
    if (t < 128) exc[t] = cnt[t];
    __syncthreads();
    for (int d = 1; d < 128; d <<= 1) {
        int v = 0;
        if (t < 128) v = exc[t] + ((t >= d) ? exc[t - d] : 0);
        __syncthreads();
        if (t < 128) exc[t] = v;
        __syncthreads();
    }
    if (t < 128) { int e = exc[t] - cnt[t]; exc[t] = e; cur[t] = e; }
    __syncthreads();
    for (int i = t; i < n; i += 256) {
        unsigned w = ebuf[start + i];
        int pos = atomicAdd(&cur[w >> 18], 1);
        stage[pos] = w & SMASK;
    }
    __syncthreads();
    for (int i = t; i < n; i += 256) ebuf[start + i] = stage[i];
    int nbase = (rel == 0) ? b * 128
              : (rel == 1) ? NBKT * 128 + b * 128
                           : 2 * NBKT * 128 + b * 64;
    if (t < nodes) { nstart[nbase + t] = start + exc[t]; ncnt[nbase + t] = cnt[t]; }
}

// ---------------- gather: 16-lane subgroups, bf16x2/lane, 8-edge stride --------
// Returns per-lane partial for channels (2*l16, 2*l16+1), already summed across
// the two subgroups (shfl_xor 16).
__device__ __forceinline__ float2 gather2(const __bf16* __restrict__ S,
                                          const unsigned* __restrict__ ebuf,
                                          int o, int n, int l16, int sub) {
    float x = 0.f, y = 0.f;
    int e = sub;
    for (; e + 6 < n; e += 8) {
        int s0 = ebuf[o + e], s1 = ebuf[o + e + 2];
        int s2 = ebuf[o + e + 4], s3 = ebuf[o + e + 6];
        bf16x2 v0 = *(const bf16x2*)(S + (size_t)s0 * 32 + 2 * l16);
        bf16x2 v1 = *(const bf16x2*)(S + (size_t)s1 * 32 + 2 * l16);
        bf16x2 v2 = *(const bf16x2*)(S + (size_t)s2 * 32 + 2 * l16);
        bf16x2 v3 = *(const bf16x2*)(S + (size_t)s3 * 32 + 2 * l16);
        x += (float)v0[0] + (float)v1[0] + (float)v2[0] + (float)v3[0];
        y += (float)v0[1] + (float)v1[1] + (float)v2[1] + (float)v3[1];
    }
    for (; e < n; e += 2) {
        bf16x2 v = *(const bf16x2*)(S + (size_t)ebuf[o + e] * 32 + 2 * l16);
        x += (float)v[0]; y += (float)v[1];
    }
    x += __shfl_xor(x, 16, 64);
    y += __shfl_xor(y, 16, 64);
    return make_float2(x, y);
}

// ---------------- unified layer-1 aggregation + scalar collapse ----------------
__global__ __launch_bounds__(256) void agg_kernel(
    const __bf16* __restrict__ YpC, const __bf16* __restrict__ YaW,
    const __bf16* __restrict__ YpD, const __bf16* __restrict__ YpR,
    const __bf16* __restrict__ YaD, const unsigned* __restrict__ ebuf,
    const int* __restrict__ nstart, const int* __restrict__ ncnt,
    const float* __restrict__ b1l_c, const float* __restrict__ b1l_w,
    const float* __restrict__ b1l_r, const float* __restrict__ uvec,
    float* __restrict__ s_c, float* __restrict__ s_r, float* __restrict__ s_w,
    int NP, int NA) {
    int g = (blockIdx.x * 256 + (int)threadIdx.x) >> 5;
    int lane32 = threadIdx.x & 31;
    int l16 = lane32 & 15, sub = lane32 >> 4, c2 = 2 * l16;
    const int NPS = NBKT * 128;
    if (g < NP) {
        int oC = nstart[g], nC = ncnt[g];
        float2 aC = gather2(YpC, ebuf, oC, nC, l16, sub);
        int oW = nstart[NPS + g], nW = ncnt[NPS + g];
        float2 aW = gather2(YaW, ebuf, oW, nW, l16, sub);
        float rC = 1.f / (float)max(nC, 1), rW = 1.f / (float)max(nW, 1);
        bf16x2 d = *(const bf16x2*)(YpD + (size_t)g * 32 + c2);
        float p0 = fmaxf(aC.x * rC + aW.x * rW + (float)d[0] + b1l_c[c2] + b1l_w[c2], 0.f);
        float p1 = fmaxf(aC.y * rC + aW.y * rW + (float)d[1] + b1l_c[c2 + 1] + b1l_w[c2 + 1], 0.f);
        float vc = p0 * uvec[c2] + p1 * uvec[c2 + 1];
        float vr = p0 * uvec[64 + c2] + p1 * uvec[64 + c2 + 1];
        for (int m = 1; m < 16; m <<= 1) {
            vc += __shfl_xor(vc, m, 64); vr += __shfl_xor(vr, m, 64);
        }
        if (lane32 == 0) { s_c[g] = vc; s_r[g] = vr; }
    } else if (g < NP + NA) {
        int ga = g - NP;
        int oR = nstart[2 * NPS + ga], nR = ncnt[2 * NPS + ga];
        float2 aR = gather2(YpR, ebuf, oR, nR, l16, sub);
        float rR = 1.f / (float)max(nR, 1);
        bf16x2 d = *(const bf16x2*)(YaD + (size_t)ga * 32 + c2);
        float p0 = fmaxf(aR.x * rR + (float)d[0] + b1l_r[c2], 0.f);
        float p1 = fmaxf(aR.y * rR + (float)d[1] + b1l_r[c2 + 1], 0.f);
        float vw = p0 * uvec[32 + c2] + p1 * uvec[32 + c2 + 1];
        for (int m = 1; m < 16; m <<= 1) vw += __shfl_xor(vw, m, 64);
        if (lane32 == 0) s_w[ga] = vw;
    }
}

// ---------------- layer-2 scalar aggregation + output: lane per node -----------
__global__ __launch_bounds__(256) void out_kernel(
    const float* __restrict__ s_c, const float* __restrict__ s_w,
    const float* __restrict__ s_r, const unsigned* __restrict__ ebuf,
    const int* __restrict__ nstart, const int* __restrict__ ncnt,
    const float* __restrict__ uvec, float* __restrict__ out, int NP) {
    int gn = blockIdx.x * 256 + threadIdx.x;
    if (gn >= NP) return;
    const int NPS = NBKT * 128;
    int o = nstart[gn], n = ncnt[gn];
    float sC = 0.f;
    for (int e = 0; e < n; ++e) sC += s_c[ebuf[o + e]];
    int o2 = nstart[NPS + gn], n2 = ncnt[NPS + gn];
    float sW = 0.f;
    for (int e = 0; e < n2; ++e) sW += s_w[ebuf[o2 + e]];
    out[gn] = sC / (float)max(n, 1) + sW / (float)max(n2, 1) + s_r[gn] + uvec[96];
}

extern "C" void kernel_launch(void* const* d_in, const int* in_sizes, int n_in,
                              void* d_out, int out_size, void* d_ws, size_t ws_size,
                              hipStream_t stream) {
    const float* x_paper  = (const float*)d_in[0];
    const float* x_author = (const float*)d_in[1];
    const int* eiC = (const int*)d_in[2];
    const int* eiW = (const int*)d_in[3];
    const int* eiR = (const int*)d_in[4];
    const float* W1l_c  = (const float*)d_in[5];
    const float* b1l_c  = (const float*)d_in[6];
    const float* W1r_c  = (const float*)d_in[7];
    const float* W1l_w  = (const float*)d_in[8];
    const float* b1l_w  = (const float*)d_in[9];
    const float* W1r_w  = (const float*)d_in[10];
    const float* W1l_r  = (const float*)d_in[11];
    const float* b1l_r  = (const float*)d_in[12];
    const float* W1r_r  = (const float*)d_in[13];
    const float* W2l_c  = (const float*)d_in[14];
    const float* b2l_c  = (const float*)d_in[15];
    const float* W2r_c  = (const float*)d_in[16];
    const float* W2l_w  = (const float*)d_in[17];
    const float* b2l_w  = (const float*)d_in[18];
    const float* W2r_w  = (const float*)d_in[19];
    // d_in[20..22] unused (author layer-2 output not consumed)
    const float* Wh = (const float*)d_in[23];
    const float* bh = (const float*)d_in[24];

    const int NP = in_sizes[0] / 128;
    const int NA = in_sizes[1] / 64;
    const int E  = in_sizes[2] / 2;
    const int npart = (E + SPAN - 1) / SPAN;
    const int nPp = (NP + 63) / 64;
    const int nPa = (NA + 63) / 64;
    const int NNODE = NBKT * 128 * 2 + NBKT * 64;

    char* p = (char*)d_ws;
    auto alloc = [&](size_t bytes) -> void* {
        void* r = (void*)p;
        p += (bytes + 255) & ~(size_t)255;
        return r;
    };
    __bf16* YpC = (__bf16*)alloc((size_t)NP * 32 * 2);
    __bf16* YpR = (__bf16*)alloc((size_t)NP * 32 * 2);
    __bf16* YpD = (__bf16*)alloc((size_t)NP * 32 * 2);
    __bf16* YaW = (__bf16*)alloc((size_t)NA * 32 * 2);
    __bf16* YaD = (__bf16*)alloc((size_t)NA * 32 * 2);
    __bf16* Bp_t = (__bf16*)alloc(96 * 128 * 2);
    __bf16* Ba_t = (__bf16*)alloc(64 * 64 * 2);
    float* uvec = (float*)alloc(128 * 4);
    float* s_c  = (float*)alloc((size_t)NP * 4);
    float* s_r  = (float*)alloc((size_t)NP * 4);
    float* s_w  = (float*)alloc((size_t)NA * 4);
    int* gcur   = (int*)alloc((size_t)3 * NBKT * 4);
    int* nstart = (int*)alloc((size_t)NNODE * 4);
    int* ncnt   = (int*)alloc((size_t)NNODE * 4);
    unsigned* ebuf = (unsigned*)alloc((size_t)3 * NBKT * CAP * 4);   // 19.2 MB

    prep_kernel<<<1, 256, 0, stream>>>(W1l_c, W1l_r, W1r_c, W1r_w, W1l_w, W1r_r,
                                       W2l_c, W2l_w, W2r_c, W2r_w, b2l_c, b2l_w,
                                       Wh, bh, Bp_t, Ba_t, uvec, gcur);

    mid_kernel<<<nPp + nPa + 3 * npart, 256, 0, stream>>>(
        x_paper, x_author, Bp_t, Ba_t, YpC, YpR, YpD, YaW, YaD,
        eiC, eiW, eiR, gcur, ebuf, NP, NA, E, nPp, nPa, npart);

    sort_kernel<<<3 * NBKT, 256, 0, stream>>>(ebuf, gcur, nstart, ncnt);

    agg_kernel<<<((NP + NA) * 32 + 255) / 256, 256, 0, stream>>>(
        YpC, YaW, YpD, YpR, YaD, ebuf, nstart, ncnt,
        b1l_c, b1l_w, b1l_r, uvec, s_c, s_r, s_w, NP, NA);

    out_kernel<<<(NP + 255) / 256, 256, 0, stream>>>(
        s_c, s_w, s_r, ebuf, nstart, ncnt, uvec, (float*)d_out, NP);
}